// Round 4
// baseline (412.914 us; speedup 1.0000x reference)
//
#include <hip/hip_runtime.h>
#include <hip/hip_bf16.h>
#include <stdint.h>

#define HID 256
#define BOT 32

typedef short short8 __attribute__((ext_vector_type(8)));
typedef unsigned short ushort8 __attribute__((ext_vector_type(8)));
typedef float floatx4 __attribute__((ext_vector_type(4)));

// fp32 -> bf16 raw bits (truncate; ~2^-8 rel err, irrelevant at 1e-5 weight scale)
__device__ __forceinline__ unsigned short f2bu(float f) {
    return (unsigned short)(__float_as_uint(f) >> 16);
}
__device__ __forceinline__ float bu2f(unsigned short u) {
    return __uint_as_float((unsigned int)u << 16);
}
// pack 8 consecutive fp32 (two float4) into a bf16 short8 fragment
__device__ __forceinline__ short8 pack8(float4 a, float4 b) {
    short8 r;
    r[0] = (short)f2bu(a.x); r[1] = (short)f2bu(a.y);
    r[2] = (short)f2bu(a.z); r[3] = (short)f2bu(a.w);
    r[4] = (short)f2bu(b.x); r[5] = (short)f2bu(b.y);
    r[6] = (short)f2bu(b.z); r[7] = (short)f2bu(b.w);
    return r;
}
__device__ __forceinline__ short8 pack8v(floatx4 a, floatx4 b) {
    short8 r;
    #pragma unroll
    for (int i = 0; i < 4; ++i) {
        r[i]     = (short)f2bu(a[i]);
        r[4 + i] = (short)f2bu(b[i]);
    }
    return r;
}

// ---------------------------------------------------------------------------
// ws layout (N=100000, E=800000 -> ~27 MB):
//   [0)              int    flags[4]  (flags[0]: edge mode; flags[1]: CSR cursor)
//   [16)             int    deg[N]
//   [16+4N)          float  dinv[N]
//   [16+8N)          int    start[N]
//   [16+12N)         int    cur[N]
//   [16+16N)         int2   srcw[E]     (src, norm-weight bits)
//   [16+16N+8E)      ushort P[N*32]     (bf16; layer-1 proj, reused as A2)
//   [16+16N+8E+64N)  ushort A1[N*32]    (bf16; layer-1 aggregate -> h1)
// ---------------------------------------------------------------------------

// int64-vs-int32 edge_index: int64 values < 2^31 have all-zero high words.
__global__ void k_detect(const int* __restrict__ ei, int* __restrict__ flags) {
    int t = threadIdx.x;           // 64 threads
    int found = 0;
    for (int i = 0; i < 8; ++i) {
        int slot = 2 * (t * 8 + i) + 1;
        if (ei[slot] != 0) found = 1;
    }
    unsigned long long b = __ballot(found);
    if (t == 0) flags[0] = (b == 0ULL) ? 1 : 0;
}

// 4 edges per thread; int4 loads of the dst column (full-width coalescing).
__global__ void k_deg(const int* __restrict__ ei, int E, int* __restrict__ deg,
                      const int* __restrict__ flags) {
    int mode = flags[0];
    int t = blockIdx.x * blockDim.x + threadIdx.x;
    int e0 = t * 4;
    if (e0 >= E) return;
    int d0, d1, d2, d3;
    if (e0 + 4 <= E) {
        if (mode) {  // int64: dst value at int index 2E + 2e
            const int4* p = (const int4*)(ei + 2 * (size_t)E + 2 * e0);
            int4 a = p[0], b = p[1];
            d0 = a.x; d1 = a.z; d2 = b.x; d3 = b.z;
        } else {     // int32: dst at E + e
            int4 a = *(const int4*)(ei + (size_t)E + e0);
            d0 = a.x; d1 = a.y; d2 = a.z; d3 = a.w;
        }
        atomicAdd(deg + d0, 1);
        atomicAdd(deg + d1, 1);
        atomicAdd(deg + d2, 1);
        atomicAdd(deg + d3, 1);
    } else {
        for (int e = e0; e < E; ++e) {
            int d = mode ? ei[2 * (size_t)E + 2 * e] : ei[(size_t)E + e];
            atomicAdd(deg + d, 1);
        }
    }
}

// Per-node CSR region allocation (block scan + one global atomic) + dinv fused.
__global__ __launch_bounds__(256) void k_alloc(const int* __restrict__ deg,
                                               float* __restrict__ dinv,
                                               int* __restrict__ start,
                                               int* __restrict__ cur,
                                               int* __restrict__ cursor, int N) {
    __shared__ int sdata[256];
    __shared__ int sbase;
    int tid = threadIdx.x;
    int i = blockIdx.x * 256 + tid;
    int d = (i < N) ? deg[i] : 0;
    if (i < N) dinv[i] = rsqrtf((float)(d + 1));  // +1 self-loop
    sdata[tid] = d;
    __syncthreads();
    for (int off = 1; off < 256; off <<= 1) {
        int t = (tid >= off) ? sdata[tid - off] : 0;
        __syncthreads();
        sdata[tid] += t;
        __syncthreads();
    }
    if (tid == 0) sbase = atomicAdd(cursor, sdata[255]);
    __syncthreads();
    if (i < N) {
        int st = sbase + sdata[tid] - d;
        start[i] = st;
        cur[i] = st;
    }
}

// 4 edges per thread; int4 loads of both src and dst columns.
__global__ void k_fill(const int* __restrict__ ei, int E,
                       const float* __restrict__ dinv,
                       int* __restrict__ cur, int2* __restrict__ srcw,
                       const int* __restrict__ flags) {
    int mode = flags[0];
    int t = blockIdx.x * blockDim.x + threadIdx.x;
    int e0 = t * 4;
    if (e0 >= E) return;
    int s[4], d[4];
    if (e0 + 4 <= E) {
        if (mode) {
            const int4* ps = (const int4*)(ei + 2 * (size_t)e0);
            const int4* pd = (const int4*)(ei + 2 * (size_t)E + 2 * e0);
            int4 sa = ps[0], sb = ps[1], da = pd[0], db = pd[1];
            s[0] = sa.x; s[1] = sa.z; s[2] = sb.x; s[3] = sb.z;
            d[0] = da.x; d[1] = da.z; d[2] = db.x; d[3] = db.z;
        } else {
            int4 sa = *(const int4*)(ei + (size_t)e0);
            int4 da = *(const int4*)(ei + (size_t)E + e0);
            s[0] = sa.x; s[1] = sa.y; s[2] = sa.z; s[3] = sa.w;
            d[0] = da.x; d[1] = da.y; d[2] = da.z; d[3] = da.w;
        }
        #pragma unroll
        for (int u = 0; u < 4; ++u) {
            float w = dinv[s[u]] * dinv[d[u]];
            int slot = atomicAdd(cur + d[u], 1);
            srcw[slot] = make_int2(s[u], __float_as_int(w));
        }
    } else {
        for (int e = e0; e < E; ++e) {
            int ss, dd;
            if (mode) { ss = ei[2 * (size_t)e]; dd = ei[2 * (size_t)E + 2 * e]; }
            else      { ss = ei[(size_t)e];     dd = ei[(size_t)E + e]; }
            float w = dinv[ss] * dinv[dd];
            int slot = atomicAdd(cur + dd, 1);
            srcw[slot] = make_int2(ss, __float_as_int(w));
        }
    }
}

// P[n,j] = sum_k x[n,k]*Wd[j,k] via mfma 16x16x32 bf16, SWAPPED operands:
// D[j_local][n_local] -> lane holds 4 consecutive j for one node -> 8B stores.
// x loads nontemporal: 102MB stream must not evict the gather tables from L2.
__global__ __launch_bounds__(256) void k_gemm_down(
    const float* __restrict__ x, const float* __restrict__ Wd,
    unsigned short* __restrict__ P, int N, int nwaves)
{
    int wid  = (blockIdx.x * 256 + threadIdx.x) >> 6;
    int lane = threadIdx.x & 63;
    int m = lane & 15, q = lane >> 4;

    // A-frag (after swap): lane m holds Wd[jt*16+m][k=ks*32+q*8..+7]
    short8 bfr[2][8];
    #pragma unroll
    for (int jt = 0; jt < 2; ++jt) {
        const float4* wr = (const float4*)(Wd + (size_t)(jt * 16 + m) * HID);
        #pragma unroll
        for (int ks = 0; ks < 8; ++ks) {
            int c = (ks * 32 + q * 8) >> 2;
            bfr[jt][ks] = pack8(wr[c], wr[c + 1]);
        }
    }

    int tiles = (N + 15) >> 4;
    for (int t = wid; t < tiles; t += nwaves) {
        int n0 = t << 4;
        int row = n0 + m; if (row >= N) row = N - 1;
        const floatx4* xr = (const floatx4*)(x + (size_t)row * HID);
        floatx4 acc0 = {0.f, 0.f, 0.f, 0.f};
        floatx4 acc1 = {0.f, 0.f, 0.f, 0.f};
        #pragma unroll
        for (int ks = 0; ks < 8; ++ks) {
            int c = (ks * 32 + q * 8) >> 2;
            floatx4 va = __builtin_nontemporal_load(xr + c);
            floatx4 vb = __builtin_nontemporal_load(xr + c + 1);
            short8 af = pack8v(va, vb);            // B[k][n=m] = x[n0+m][k]
            acc0 = __builtin_amdgcn_mfma_f32_16x16x32_bf16(bfr[0][ks], af, acc0, 0, 0, 0);
            acc1 = __builtin_amdgcn_mfma_f32_16x16x32_bf16(bfr[1][ks], af, acc1, 0, 0, 0);
        }
        // D: col=m -> node n0+m; row=q*4+r -> j = jt*16 + q*4 + r
        if (n0 + m < N) {
            unsigned int* pr = (unsigned int*)(P + (size_t)(n0 + m) * BOT);
            uint2 v0, v1;
            v0.x = (unsigned int)f2bu(acc0[0]) | ((unsigned int)f2bu(acc0[1]) << 16);
            v0.y = (unsigned int)f2bu(acc0[2]) | ((unsigned int)f2bu(acc0[3]) << 16);
            v1.x = (unsigned int)f2bu(acc1[0]) | ((unsigned int)f2bu(acc1[1]) << 16);
            v1.y = (unsigned int)f2bu(acc1[2]) | ((unsigned int)f2bu(acc1[3]) << 16);
            *(uint2*)(pr + q * 2)     = v0;   // j = q*4..q*4+3
            *(uint2*)(pr + 8 + q * 2) = v1;   // j = 16+q*4..16+q*4+3
        }
    }
}

// Gather-aggregate over CSR: 4 threads per node, each owns 8 of 32 features.
// Unroll-8 masked: 8 independent srcw loads then 8 independent 16B gathers in
// flight per iteration (mean degree 8 -> typically one iteration).
__global__ __launch_bounds__(256) void k_gather(
    const unsigned short* __restrict__ feat, const float* __restrict__ dinv,
    const int* __restrict__ start, const int* __restrict__ endp,
    const int2* __restrict__ srcw, const float* __restrict__ bias,
    unsigned short* __restrict__ dst, int N, int relu_bias)
{
    int t = blockIdx.x * 256 + threadIdx.x;
    int n = t >> 2, jq = (t & 3) * 8;
    if (n >= N) return;
    float di = dinv[n];
    float w0 = di * di;
    float acc[8];
    ushort8 sv = *(const ushort8*)(feat + (size_t)n * BOT + jq);
    #pragma unroll
    for (int i = 0; i < 8; ++i) acc[i] = w0 * bu2f(sv[i]);
    int k = start[n], en = endp[n];
    while (k < en) {
        int2 p[8];
        #pragma unroll
        for (int u = 0; u < 8; ++u) {
            int kk = k + u;
            int safe = kk < en ? kk : en - 1;   // en-1 valid: loop entered => deg>0
            p[u] = srcw[safe];
            if (kk >= en) p[u].y = 0;          // weight 0 for masked lanes
        }
        ushort8 f[8];
        #pragma unroll
        for (int u = 0; u < 8; ++u)
            f[u] = *(const ushort8*)(feat + (size_t)p[u].x * BOT + jq);
        #pragma unroll
        for (int u = 0; u < 8; ++u) {
            float w = __int_as_float(p[u].y);
            #pragma unroll
            for (int i = 0; i < 8; ++i) acc[i] += w * bu2f(f[u][i]);
        }
        k += 8;
    }
    if (relu_bias) {
        #pragma unroll
        for (int i = 0; i < 8; ++i) {
            float a = acc[i] + bias[jq + i];
            acc[i] = a > 0.f ? a : 0.f;
        }
    }
    ushort8 o;
    #pragma unroll
    for (int i = 0; i < 8; ++i) o[i] = f2bu(acc[i]);
    *(ushort8*)(dst + (size_t)n * BOT + jq) = o;
}

// out[n,f] = sum_j A2[n,j]*Wup[f,j] + bu[f] + x[n,f].
// SWAPPED operands: lane holds 4 consecutive f for one node -> NT float4 x-load
// + 16B NT out-store per ft-tile. TWO waves per 16-node tile (8 ft each).
__global__ __launch_bounds__(256) void k_out(
    const unsigned short* __restrict__ A2, const float* __restrict__ x,
    const float* __restrict__ Wup, const float* __restrict__ bup,
    float* __restrict__ out, int N)
{
    int gw   = (blockIdx.x * 256 + threadIdx.x) >> 6;
    int lane = threadIdx.x & 63;
    int m = lane & 15, q = lane >> 4;
    int tiles = (N + 15) >> 4;
    int t = gw >> 1, h = gw & 1;
    if (t >= tiles) return;

    int n0 = t << 4;
    int arow = n0 + m; if (arow >= N) arow = N - 1;
    short8 af = *(const short8*)(A2 + (size_t)arow * BOT + q * 8);  // B[k][n=m]
    const floatx4* xrow = (const floatx4*)(x + (size_t)arow * HID);
    floatx4* orow = (floatx4*)(out + (size_t)arow * HID);
    bool ok = (n0 + m) < N;
    #pragma unroll
    for (int i = 0; i < 8; ++i) {
        int ft = h * 8 + i;
        const float4* wr = (const float4*)(Wup + (size_t)(ft * 16 + m) * BOT);
        short8 bfr = pack8(wr[q * 2], wr[q * 2 + 1]);
        floatx4 acc = {0.f, 0.f, 0.f, 0.f};
        acc = __builtin_amdgcn_mfma_f32_16x16x32_bf16(bfr, af, acc, 0, 0, 0);
        // D: col=m -> node n0+m; row=q*4+r -> f = ft*16 + q*4 + r
        if (ok) {
            int c = ft * 4 + q;                      // float4 index in row
            floatx4 xv = __builtin_nontemporal_load(xrow + c);
            float4 bb = *(const float4*)(bup + ft * 16 + q * 4);
            floatx4 res;
            res[0] = acc[0] + bb.x + xv[0];
            res[1] = acc[1] + bb.y + xv[1];
            res[2] = acc[2] + bb.z + xv[2];
            res[3] = acc[3] + bb.w + xv[3];
            __builtin_nontemporal_store(res, &orow[c]);
        }
    }
}

extern "C" void kernel_launch(void* const* d_in, const int* in_sizes, int n_in,
                              void* d_out, int out_size, void* d_ws, size_t ws_size,
                              hipStream_t stream) {
    const float* x  = (const float*)d_in[0];
    const int*   ei = (const int*)d_in[1];
    const float* Wd = (const float*)d_in[2];
    const float* bd = (const float*)d_in[3];
    const float* Wu = (const float*)d_in[4];
    const float* bu = (const float*)d_in[5];
    float* out = (float*)d_out;

    int N = in_sizes[0] / HID;   // 100000
    int E = in_sizes[1] / 2;     // 800000

    char* ws = (char*)d_ws;
    int*   flags = (int*)ws;                                  // flags[1] = CSR cursor
    int*   deg   = (int*)(ws + 16);
    float* dinv  = (float*)(ws + 16 + (size_t)N * 4);
    int*   startp= (int*)(ws + 16 + (size_t)N * 8);
    int*   curp  = (int*)(ws + 16 + (size_t)N * 12);
    int2*  srcw  = (int2*)(ws + 16 + (size_t)N * 16);
    unsigned short* P  = (unsigned short*)(ws + 16 + (size_t)N * 16 + (size_t)E * 8);
    unsigned short* A1 = (unsigned short*)(ws + 16 + (size_t)N * 16 + (size_t)E * 8 + (size_t)N * 64);

    (void)hipMemsetAsync(ws, 0, 16 + (size_t)N * 4, stream);  // flags + cursor + deg
    k_detect<<<1, 64, 0, stream>>>(ei, flags);
    int ethreads = (E + 3) / 4;                 // 4 edges per thread
    k_deg<<<(ethreads + 255) / 256, 256, 0, stream>>>(ei, E, deg, flags);

    // CSR build (destination-ordered); dinv fused into alloc
    k_alloc<<<(N + 255) / 256, 256, 0, stream>>>(deg, dinv, startp, curp, flags + 1, N);
    k_fill<<<(ethreads + 255) / 256, 256, 0, stream>>>(ei, E, dinv, curp, srcw, flags);

    // Layer 1: P = x @ Wd^T (MFMA) ; h1 = relu(gather(P) + bd)
    int tiles = (N + 15) / 16;                  // 6250
    int gblocks = (tiles + 3) / 4;              // 1 tile per wave
    k_gemm_down<<<gblocks, 256, 0, stream>>>(x, Wd, P, N, gblocks * 4);
    int gthreads = N * 4;   // 4 threads per node
    k_gather<<<(gthreads + 255) / 256, 256, 0, stream>>>(P, dinv, startp, curp, srcw, bd, A1, N, 1);

    // Layer 2: A2 = gather(h1)  (reuses P buffer)
    k_gather<<<(gthreads + 255) / 256, 256, 0, stream>>>(A1, dinv, startp, curp, srcw, bd, P, N, 0);

    // out = A2 @ Wu^T + bu + x  (MFMA epilogue-fused), 2 waves per tile
    int oblocks = (tiles * 2 + 3) / 4;          // 3125
    k_out<<<oblocks, 256, 0, stream>>>(P, x, Wu, bu, out, N);
}

// Round 5
// 378.099 us; speedup vs baseline: 1.0921x; 1.0921x over previous
//
#include <hip/hip_runtime.h>
#include <hip/hip_bf16.h>
#include <stdint.h>

#define HID 256
#define BOT 32

typedef short short8 __attribute__((ext_vector_type(8)));
typedef unsigned short ushort8 __attribute__((ext_vector_type(8)));
typedef float floatx4 __attribute__((ext_vector_type(4)));

// fp32 -> bf16 raw bits (truncate; ~2^-8 rel err, irrelevant at 1e-5 weight scale)
__device__ __forceinline__ unsigned short f2bu(float f) {
    return (unsigned short)(__float_as_uint(f) >> 16);
}
__device__ __forceinline__ float bu2f(unsigned short u) {
    return __uint_as_float((unsigned int)u << 16);
}
// pack 8 consecutive fp32 (two float4) into a bf16 short8 fragment
__device__ __forceinline__ short8 pack8(float4 a, float4 b) {
    short8 r;
    r[0] = (short)f2bu(a.x); r[1] = (short)f2bu(a.y);
    r[2] = (short)f2bu(a.z); r[3] = (short)f2bu(a.w);
    r[4] = (short)f2bu(b.x); r[5] = (short)f2bu(b.y);
    r[6] = (short)f2bu(b.z); r[7] = (short)f2bu(b.w);
    return r;
}

// ---------------------------------------------------------------------------
// ws layout (N=100000, E=800000 -> ~27 MB):
//   [0)              int    flags[4]  (flags[0]: edge mode; flags[1]: CSR cursor)
//   [16)             int    deg[N]
//   [16+4N)          float  dinv[N]
//   [16+8N)          int    start[N]
//   [16+12N)         int    cur[N]
//   [16+16N)         int2   srcw[E]     (src, norm-weight bits)
//   [16+16N+8E)      ushort P[N*32]     (bf16; layer-1 proj, reused as A2)
//   [16+16N+8E+64N)  ushort A1[N*32]    (bf16; layer-1 aggregate -> h1)
// ---------------------------------------------------------------------------

// int64-vs-int32 edge_index: int64 values < 2^31 have all-zero high words.
__global__ void k_detect(const int* __restrict__ ei, int* __restrict__ flags) {
    int t = threadIdx.x;           // 64 threads
    int found = 0;
    for (int i = 0; i < 8; ++i) {
        int slot = 2 * (t * 8 + i) + 1;
        if (ei[slot] != 0) found = 1;
    }
    unsigned long long b = __ballot(found);
    if (t == 0) flags[0] = (b == 0ULL) ? 1 : 0;
}

// 4 edges per thread; int4 loads of the dst column (full-width coalescing).
__global__ void k_deg(const int* __restrict__ ei, int E, int* __restrict__ deg,
                      const int* __restrict__ flags) {
    int mode = flags[0];
    int t = blockIdx.x * blockDim.x + threadIdx.x;
    int e0 = t * 4;
    if (e0 >= E) return;
    int d0, d1, d2, d3;
    if (e0 + 4 <= E) {
        if (mode) {  // int64: dst value at int index 2E + 2e
            const int4* p = (const int4*)(ei + 2 * (size_t)E + 2 * e0);
            int4 a = p[0], b = p[1];
            d0 = a.x; d1 = a.z; d2 = b.x; d3 = b.z;
        } else {     // int32: dst at E + e
            int4 a = *(const int4*)(ei + (size_t)E + e0);
            d0 = a.x; d1 = a.y; d2 = a.z; d3 = a.w;
        }
        atomicAdd(deg + d0, 1);
        atomicAdd(deg + d1, 1);
        atomicAdd(deg + d2, 1);
        atomicAdd(deg + d3, 1);
    } else {
        for (int e = e0; e < E; ++e) {
            int d = mode ? ei[2 * (size_t)E + 2 * e] : ei[(size_t)E + e];
            atomicAdd(deg + d, 1);
        }
    }
}

// Per-node CSR region allocation (block scan + one global atomic) + dinv fused.
__global__ __launch_bounds__(256) void k_alloc(const int* __restrict__ deg,
                                               float* __restrict__ dinv,
                                               int* __restrict__ start,
                                               int* __restrict__ cur,
                                               int* __restrict__ cursor, int N) {
    __shared__ int sdata[256];
    __shared__ int sbase;
    int tid = threadIdx.x;
    int i = blockIdx.x * 256 + tid;
    int d = (i < N) ? deg[i] : 0;
    if (i < N) dinv[i] = rsqrtf((float)(d + 1));  // +1 self-loop
    sdata[tid] = d;
    __syncthreads();
    for (int off = 1; off < 256; off <<= 1) {
        int t = (tid >= off) ? sdata[tid - off] : 0;
        __syncthreads();
        sdata[tid] += t;
        __syncthreads();
    }
    if (tid == 0) sbase = atomicAdd(cursor, sdata[255]);
    __syncthreads();
    if (i < N) {
        int st = sbase + sdata[tid] - d;
        start[i] = st;
        cur[i] = st;
    }
}

// 4 edges per thread; int4 loads of both src and dst columns.
__global__ void k_fill(const int* __restrict__ ei, int E,
                       const float* __restrict__ dinv,
                       int* __restrict__ cur, int2* __restrict__ srcw,
                       const int* __restrict__ flags) {
    int mode = flags[0];
    int t = blockIdx.x * blockDim.x + threadIdx.x;
    int e0 = t * 4;
    if (e0 >= E) return;
    int s[4], d[4];
    if (e0 + 4 <= E) {
        if (mode) {
            const int4* ps = (const int4*)(ei + 2 * (size_t)e0);
            const int4* pd = (const int4*)(ei + 2 * (size_t)E + 2 * e0);
            int4 sa = ps[0], sb = ps[1], da = pd[0], db = pd[1];
            s[0] = sa.x; s[1] = sa.z; s[2] = sb.x; s[3] = sb.z;
            d[0] = da.x; d[1] = da.z; d[2] = db.x; d[3] = db.z;
        } else {
            int4 sa = *(const int4*)(ei + (size_t)e0);
            int4 da = *(const int4*)(ei + (size_t)E + e0);
            s[0] = sa.x; s[1] = sa.y; s[2] = sa.z; s[3] = sa.w;
            d[0] = da.x; d[1] = da.y; d[2] = da.z; d[3] = da.w;
        }
        #pragma unroll
        for (int u = 0; u < 4; ++u) {
            float w = dinv[s[u]] * dinv[d[u]];
            int slot = atomicAdd(cur + d[u], 1);
            srcw[slot] = make_int2(s[u], __float_as_int(w));
        }
    } else {
        for (int e = e0; e < E; ++e) {
            int ss, dd;
            if (mode) { ss = ei[2 * (size_t)e]; dd = ei[2 * (size_t)E + 2 * e]; }
            else      { ss = ei[(size_t)e];     dd = ei[(size_t)E + e]; }
            float w = dinv[ss] * dinv[dd];
            int slot = atomicAdd(cur + dd, 1);
            srcw[slot] = make_int2(ss, __float_as_int(w));
        }
    }
}

// P[n,j] = sum_k x[n,k]*Wd[j,k] via mfma 16x16x32 bf16, SWAPPED operands:
// D[j_local][n_local] -> lane holds 4 consecutive j for one node -> 8B stores.
// Plain (cached) x loads: they populate L3 so k_out's re-read of x is L3-hot.
__global__ __launch_bounds__(256) void k_gemm_down(
    const float* __restrict__ x, const float* __restrict__ Wd,
    unsigned short* __restrict__ P, int N, int nwaves)
{
    int wid  = (blockIdx.x * 256 + threadIdx.x) >> 6;
    int lane = threadIdx.x & 63;
    int m = lane & 15, q = lane >> 4;

    // A-frag (after swap): lane m holds Wd[jt*16+m][k=ks*32+q*8..+7]
    short8 bfr[2][8];
    #pragma unroll
    for (int jt = 0; jt < 2; ++jt) {
        const float4* wr = (const float4*)(Wd + (size_t)(jt * 16 + m) * HID);
        #pragma unroll
        for (int ks = 0; ks < 8; ++ks) {
            int c = (ks * 32 + q * 8) >> 2;
            bfr[jt][ks] = pack8(wr[c], wr[c + 1]);
        }
    }

    int tiles = (N + 15) >> 4;
    for (int t = wid; t < tiles; t += nwaves) {
        int n0 = t << 4;
        int row = n0 + m; if (row >= N) row = N - 1;
        const float4* xr = (const float4*)(x + (size_t)row * HID);
        floatx4 acc0 = {0.f, 0.f, 0.f, 0.f};
        floatx4 acc1 = {0.f, 0.f, 0.f, 0.f};
        #pragma unroll
        for (int ks = 0; ks < 8; ++ks) {
            int c = (ks * 32 + q * 8) >> 2;
            short8 af = pack8(xr[c], xr[c + 1]);   // B[k][n=m] = x[n0+m][k]
            acc0 = __builtin_amdgcn_mfma_f32_16x16x32_bf16(bfr[0][ks], af, acc0, 0, 0, 0);
            acc1 = __builtin_amdgcn_mfma_f32_16x16x32_bf16(bfr[1][ks], af, acc1, 0, 0, 0);
        }
        // D: col=m -> node n0+m; row=q*4+r -> j = jt*16 + q*4 + r
        if (n0 + m < N) {
            unsigned int* pr = (unsigned int*)(P + (size_t)(n0 + m) * BOT);
            uint2 v0, v1;
            v0.x = (unsigned int)f2bu(acc0[0]) | ((unsigned int)f2bu(acc0[1]) << 16);
            v0.y = (unsigned int)f2bu(acc0[2]) | ((unsigned int)f2bu(acc0[3]) << 16);
            v1.x = (unsigned int)f2bu(acc1[0]) | ((unsigned int)f2bu(acc1[1]) << 16);
            v1.y = (unsigned int)f2bu(acc1[2]) | ((unsigned int)f2bu(acc1[3]) << 16);
            *(uint2*)(pr + q * 2)     = v0;   // j = q*4..q*4+3
            *(uint2*)(pr + 8 + q * 2) = v1;   // j = 16+q*4..16+q*4+3
        }
    }
}

// Gather-aggregate over CSR: 4 threads per node, each owns 8 of 32 features.
// Masked unroll-4: 4 independent srcw loads then 4 independent 16B gathers in
// flight per iteration; expected waste ~1.7 loads/node (vs ~3.2 at unroll-8).
__global__ __launch_bounds__(256) void k_gather(
    const unsigned short* __restrict__ feat, const float* __restrict__ dinv,
    const int* __restrict__ start, const int* __restrict__ endp,
    const int2* __restrict__ srcw, const float* __restrict__ bias,
    unsigned short* __restrict__ dst, int N, int relu_bias)
{
    int t = blockIdx.x * 256 + threadIdx.x;
    int n = t >> 2, jq = (t & 3) * 8;
    if (n >= N) return;
    float di = dinv[n];
    float w0 = di * di;
    float acc[8];
    ushort8 sv = *(const ushort8*)(feat + (size_t)n * BOT + jq);
    #pragma unroll
    for (int i = 0; i < 8; ++i) acc[i] = w0 * bu2f(sv[i]);
    int k = start[n], en = endp[n];
    while (k < en) {
        int2 p[4];
        #pragma unroll
        for (int u = 0; u < 4; ++u) {
            int kk = k + u;
            int safe = kk < en ? kk : en - 1;   // en-1 valid: loop entered => deg>0
            p[u] = srcw[safe];
            if (kk >= en) p[u].y = 0;          // weight 0 for masked lanes
        }
        ushort8 f[4];
        #pragma unroll
        for (int u = 0; u < 4; ++u)
            f[u] = *(const ushort8*)(feat + (size_t)p[u].x * BOT + jq);
        #pragma unroll
        for (int u = 0; u < 4; ++u) {
            float w = __int_as_float(p[u].y);
            #pragma unroll
            for (int i = 0; i < 8; ++i) acc[i] += w * bu2f(f[u][i]);
        }
        k += 4;
    }
    if (relu_bias) {
        #pragma unroll
        for (int i = 0; i < 8; ++i) {
            float a = acc[i] + bias[jq + i];
            acc[i] = a > 0.f ? a : 0.f;
        }
    }
    ushort8 o;
    #pragma unroll
    for (int i = 0; i < 8; ++i) o[i] = f2bu(acc[i]);
    *(ushort8*)(dst + (size_t)n * BOT + jq) = o;
}

// out[n,f] = sum_j A2[n,j]*Wup[f,j] + bu[f] + x[n,f].
// SWAPPED operands: lane holds 4 consecutive f for one node -> cached float4
// x-load (L3-hot from k_gemm_down) + 16B NT out-store per ft-tile.
// TWO waves per 16-node tile (8 ft each) -> 12500 waves, 67% occupancy.
__global__ __launch_bounds__(256) void k_out(
    const unsigned short* __restrict__ A2, const float* __restrict__ x,
    const float* __restrict__ Wup, const float* __restrict__ bup,
    float* __restrict__ out, int N)
{
    int gw   = (blockIdx.x * 256 + threadIdx.x) >> 6;
    int lane = threadIdx.x & 63;
    int m = lane & 15, q = lane >> 4;
    int tiles = (N + 15) >> 4;
    int t = gw >> 1, h = gw & 1;
    if (t >= tiles) return;

    int n0 = t << 4;
    int arow = n0 + m; if (arow >= N) arow = N - 1;
    short8 af = *(const short8*)(A2 + (size_t)arow * BOT + q * 8);  // B[k][n=m]
    const float4* xrow = (const float4*)(x + (size_t)arow * HID);
    floatx4* orow = (floatx4*)(out + (size_t)arow * HID);
    bool ok = (n0 + m) < N;
    #pragma unroll
    for (int i = 0; i < 8; ++i) {
        int ft = h * 8 + i;
        const float4* wr = (const float4*)(Wup + (size_t)(ft * 16 + m) * BOT);
        short8 bfr = pack8(wr[q * 2], wr[q * 2 + 1]);
        floatx4 acc = {0.f, 0.f, 0.f, 0.f};
        acc = __builtin_amdgcn_mfma_f32_16x16x32_bf16(bfr, af, acc, 0, 0, 0);
        // D: col=m -> node n0+m; row=q*4+r -> f = ft*16 + q*4 + r
        if (ok) {
            int c = ft * 4 + q;                      // float4 index in row
            float4 xv = xrow[c];
            float4 bb = *(const float4*)(bup + ft * 16 + q * 4);
            floatx4 res;
            res[0] = acc[0] + bb.x + xv.x;
            res[1] = acc[1] + bb.y + xv.y;
            res[2] = acc[2] + bb.z + xv.z;
            res[3] = acc[3] + bb.w + xv.w;
            __builtin_nontemporal_store(res, &orow[c]);
        }
    }
}

extern "C" void kernel_launch(void* const* d_in, const int* in_sizes, int n_in,
                              void* d_out, int out_size, void* d_ws, size_t ws_size,
                              hipStream_t stream) {
    const float* x  = (const float*)d_in[0];
    const int*   ei = (const int*)d_in[1];
    const float* Wd = (const float*)d_in[2];
    const float* bd = (const float*)d_in[3];
    const float* Wu = (const float*)d_in[4];
    const float* bu = (const float*)d_in[5];
    float* out = (float*)d_out;

    int N = in_sizes[0] / HID;   // 100000
    int E = in_sizes[1] / 2;     // 800000

    char* ws = (char*)d_ws;
    int*   flags = (int*)ws;                                  // flags[1] = CSR cursor
    int*   deg   = (int*)(ws + 16);
    float* dinv  = (float*)(ws + 16 + (size_t)N * 4);
    int*   startp= (int*)(ws + 16 + (size_t)N * 8);
    int*   curp  = (int*)(ws + 16 + (size_t)N * 12);
    int2*  srcw  = (int2*)(ws + 16 + (size_t)N * 16);
    unsigned short* P  = (unsigned short*)(ws + 16 + (size_t)N * 16 + (size_t)E * 8);
    unsigned short* A1 = (unsigned short*)(ws + 16 + (size_t)N * 16 + (size_t)E * 8 + (size_t)N * 64);

    (void)hipMemsetAsync(ws, 0, 16 + (size_t)N * 4, stream);  // flags + cursor + deg
    k_detect<<<1, 64, 0, stream>>>(ei, flags);
    int ethreads = (E + 3) / 4;                 // 4 edges per thread
    k_deg<<<(ethreads + 255) / 256, 256, 0, stream>>>(ei, E, deg, flags);

    // CSR build (destination-ordered); dinv fused into alloc
    k_alloc<<<(N + 255) / 256, 256, 0, stream>>>(deg, dinv, startp, curp, flags + 1, N);
    k_fill<<<(ethreads + 255) / 256, 256, 0, stream>>>(ei, E, dinv, curp, srcw, flags);

    // Layer 1: P = x @ Wd^T (MFMA) ; h1 = relu(gather(P) + bd)
    int tiles = (N + 15) / 16;                  // 6250
    int gblocks = (tiles + 3) / 4;              // 1 tile per wave
    k_gemm_down<<<gblocks, 256, 0, stream>>>(x, Wd, P, N, gblocks * 4);
    int gthreads = N * 4;   // 4 threads per node
    k_gather<<<(gthreads + 255) / 256, 256, 0, stream>>>(P, dinv, startp, curp, srcw, bd, A1, N, 1);

    // Layer 2: A2 = gather(h1)  (reuses P buffer)
    k_gather<<<(gthreads + 255) / 256, 256, 0, stream>>>(A1, dinv, startp, curp, srcw, bd, P, N, 0);

    // out = A2 @ Wu^T + bu + x  (MFMA epilogue-fused), 2 waves per tile
    int oblocks = (tiles * 2 + 3) / 4;          // 3125
    k_out<<<oblocks, 256, 0, stream>>>(P, x, Wu, bu, out, N);
}

// Round 6
// 353.508 us; speedup vs baseline: 1.1680x; 1.0696x over previous
//
#include <hip/hip_runtime.h>
#include <hip/hip_bf16.h>
#include <stdint.h>

#define HID 256
#define BOT 32

typedef short short8 __attribute__((ext_vector_type(8)));
typedef unsigned short ushort8 __attribute__((ext_vector_type(8)));
typedef float floatx4 __attribute__((ext_vector_type(4)));

// fp32 -> bf16 raw bits (truncate; ~2^-8 rel err, irrelevant at 1e-5 weight scale)
__device__ __forceinline__ unsigned short f2bu(float f) {
    return (unsigned short)(__float_as_uint(f) >> 16);
}
__device__ __forceinline__ float bu2f(unsigned short u) {
    return __uint_as_float((unsigned int)u << 16);
}
// pack 8 consecutive fp32 (two float4) into a bf16 short8 fragment
__device__ __forceinline__ short8 pack8(float4 a, float4 b) {
    short8 r;
    r[0] = (short)f2bu(a.x); r[1] = (short)f2bu(a.y);
    r[2] = (short)f2bu(a.z); r[3] = (short)f2bu(a.w);
    r[4] = (short)f2bu(b.x); r[5] = (short)f2bu(b.y);
    r[6] = (short)f2bu(b.z); r[7] = (short)f2bu(b.w);
    return r;
}

// Per-block int64-vs-int32 detection: int64 values < 2^31 have all-zero high
// words; check the first 512 odd int slots (L2-hot, one wave does it).
__device__ __forceinline__ int detect_mode(const int* __restrict__ ei, int* smode) {
    if (threadIdx.x < 64) {
        int found = 0;
        #pragma unroll
        for (int i = 0; i < 8; ++i) {
            int slot = 2 * (threadIdx.x * 8 + i) + 1;
            if (ei[slot] != 0) found = 1;
        }
        unsigned long long b = __ballot(found);
        if (threadIdx.x == 0) *smode = (b == 0ULL) ? 1 : 0;
    }
    __syncthreads();
    return *smode;
}

// ---------------------------------------------------------------------------
// ws layout (N=100000, E=800000 -> ~27 MB):
//   [0)              int    flags[4]  (flags[1]: CSR cursor)
//   [16)             int    deg[N]
//   [16+4N)          float  dinv[N]
//   [16+8N)          int    start[N]
//   [16+12N)         int    cur[N]
//   [16+16N)         int2   srcw[E]     (src, norm-weight bits)
//   [16+16N+8E)      ushort P[N*32]     (bf16; layer-1 proj)
//   [16+16N+8E+64N)  ushort A1[N*32]    (bf16; layer-1 aggregate -> h1)
// ---------------------------------------------------------------------------

// 1 edge/thread: the atomic+scattered-store chain is latency-bound -> max TLP.
__global__ __launch_bounds__(256) void k_deg(const int* __restrict__ ei, int E,
                                             int* __restrict__ deg) {
    __shared__ int smode;
    int mode = detect_mode(ei, &smode);
    int e = blockIdx.x * 256 + threadIdx.x;
    if (e >= E) return;
    int d = mode ? ei[2 * (size_t)E + 2 * e] : ei[(size_t)E + e];
    atomicAdd(deg + d, 1);
}

// Per-node CSR region allocation (block scan + one global atomic) + dinv fused.
__global__ __launch_bounds__(256) void k_alloc(const int* __restrict__ deg,
                                               float* __restrict__ dinv,
                                               int* __restrict__ start,
                                               int* __restrict__ cur,
                                               int* __restrict__ cursor, int N) {
    __shared__ int sdata[256];
    __shared__ int sbase;
    int tid = threadIdx.x;
    int i = blockIdx.x * 256 + tid;
    int d = (i < N) ? deg[i] : 0;
    if (i < N) dinv[i] = rsqrtf((float)(d + 1));  // +1 self-loop
    sdata[tid] = d;
    __syncthreads();
    for (int off = 1; off < 256; off <<= 1) {
        int t = (tid >= off) ? sdata[tid - off] : 0;
        __syncthreads();
        sdata[tid] += t;
        __syncthreads();
    }
    if (tid == 0) sbase = atomicAdd(cursor, sdata[255]);
    __syncthreads();
    if (i < N) {
        int st = sbase + sdata[tid] - d;
        start[i] = st;
        cur[i] = st;
    }
}

// Heterogeneous kernel: blocks [0,gemmBlocks) run the down-GEMM, the rest run
// CSR fill (1 edge/thread). Both are latency-bound and independent -> fusing
// them co-schedules their waves so each hides the other's stalls.
__global__ __launch_bounds__(256) void k_fill_gemm(
    const int* __restrict__ ei, int E,
    const float* __restrict__ dinv, int* __restrict__ cur,
    int2* __restrict__ srcw,
    const float* __restrict__ x, const float* __restrict__ Wd,
    unsigned short* __restrict__ P, int N, int gemmBlocks, int gemmWaves)
{
    if (blockIdx.x >= gemmBlocks) {
        // ---- CSR fill ----
        __shared__ int smode;
        int mode = detect_mode(ei, &smode);
        int e = (blockIdx.x - gemmBlocks) * 256 + threadIdx.x;
        if (e >= E) return;
        int s, d;
        if (mode) { s = ei[2 * (size_t)e]; d = ei[2 * (size_t)E + 2 * e]; }
        else      { s = ei[(size_t)e];     d = ei[(size_t)E + e]; }
        float w = dinv[s] * dinv[d];
        int slot = atomicAdd(cur + d, 1);
        srcw[slot] = make_int2(s, __float_as_int(w));
        return;
    }

    // ---- P[n,j] = sum_k x[n,k]*Wd[j,k], mfma 16x16x32 bf16, swapped ops:
    // D col=m -> node, row=q*4+r -> j. Cached x loads populate L3 for reuse.
    int wid  = (blockIdx.x * 256 + threadIdx.x) >> 6;
    int lane = threadIdx.x & 63;
    int m = lane & 15, q = lane >> 4;

    short8 bfr[2][8];   // lane m holds Wd[jt*16+m][k=ks*32+q*8..+7]
    #pragma unroll
    for (int jt = 0; jt < 2; ++jt) {
        const float4* wr = (const float4*)(Wd + (size_t)(jt * 16 + m) * HID);
        #pragma unroll
        for (int ks = 0; ks < 8; ++ks) {
            int c = (ks * 32 + q * 8) >> 2;
            bfr[jt][ks] = pack8(wr[c], wr[c + 1]);
        }
    }

    int tiles = (N + 15) >> 4;
    for (int t = wid; t < tiles; t += gemmWaves) {
        int n0 = t << 4;
        int row = n0 + m; if (row >= N) row = N - 1;
        const float4* xr = (const float4*)(x + (size_t)row * HID);
        floatx4 acc0 = {0.f, 0.f, 0.f, 0.f};
        floatx4 acc1 = {0.f, 0.f, 0.f, 0.f};
        #pragma unroll
        for (int ks = 0; ks < 8; ++ks) {
            int c = (ks * 32 + q * 8) >> 2;
            short8 af = pack8(xr[c], xr[c + 1]);   // B[k][n=m] = x[n0+m][k]
            acc0 = __builtin_amdgcn_mfma_f32_16x16x32_bf16(bfr[0][ks], af, acc0, 0, 0, 0);
            acc1 = __builtin_amdgcn_mfma_f32_16x16x32_bf16(bfr[1][ks], af, acc1, 0, 0, 0);
        }
        if (n0 + m < N) {
            unsigned int* pr = (unsigned int*)(P + (size_t)(n0 + m) * BOT);
            uint2 v0, v1;
            v0.x = (unsigned int)f2bu(acc0[0]) | ((unsigned int)f2bu(acc0[1]) << 16);
            v0.y = (unsigned int)f2bu(acc0[2]) | ((unsigned int)f2bu(acc0[3]) << 16);
            v1.x = (unsigned int)f2bu(acc1[0]) | ((unsigned int)f2bu(acc1[1]) << 16);
            v1.y = (unsigned int)f2bu(acc1[2]) | ((unsigned int)f2bu(acc1[3]) << 16);
            *(uint2*)(pr + q * 2)     = v0;   // j = q*4..q*4+3
            *(uint2*)(pr + 8 + q * 2) = v1;   // j = 16+q*4..16+q*4+3
        }
    }
}

// Gather-aggregate over CSR: 4 threads per node, each owns 8 of 32 features.
// Masked unroll-4: 4 independent srcw loads + 4 independent 16B gathers/iter.
__global__ __launch_bounds__(256) void k_gather(
    const unsigned short* __restrict__ feat, const float* __restrict__ dinv,
    const int* __restrict__ start, const int* __restrict__ endp,
    const int2* __restrict__ srcw, const float* __restrict__ bias,
    unsigned short* __restrict__ dst, int N, int relu_bias)
{
    int t = blockIdx.x * 256 + threadIdx.x;
    int n = t >> 2, jq = (t & 3) * 8;
    if (n >= N) return;
    float di = dinv[n];
    float w0 = di * di;
    float acc[8];
    ushort8 sv = *(const ushort8*)(feat + (size_t)n * BOT + jq);
    #pragma unroll
    for (int i = 0; i < 8; ++i) acc[i] = w0 * bu2f(sv[i]);
    int k = start[n], en = endp[n];
    while (k < en) {
        int2 p[4];
        #pragma unroll
        for (int u = 0; u < 4; ++u) {
            int kk = k + u;
            int safe = kk < en ? kk : en - 1;   // en-1 valid: loop entered => deg>0
            p[u] = srcw[safe];
            if (kk >= en) p[u].y = 0;          // weight 0 for masked lanes
        }
        ushort8 f[4];
        #pragma unroll
        for (int u = 0; u < 4; ++u)
            f[u] = *(const ushort8*)(feat + (size_t)p[u].x * BOT + jq);
        #pragma unroll
        for (int u = 0; u < 4; ++u) {
            float w = __int_as_float(p[u].y);
            #pragma unroll
            for (int i = 0; i < 8; ++i) acc[i] += w * bu2f(f[u][i]);
        }
        k += 4;
    }
    if (relu_bias) {
        #pragma unroll
        for (int i = 0; i < 8; ++i) {
            float a = acc[i] + bias[jq + i];
            acc[i] = a > 0.f ? a : 0.f;
        }
    }
    ushort8 o;
    #pragma unroll
    for (int i = 0; i < 8; ++i) o[i] = f2bu(acc[i]);
    *(ushort8*)(dst + (size_t)n * BOT + jq) = o;
}

// FUSED gather-2 + up-projection + skip: out[n,:] depends only on A2[n,:], and
// the gather lane layout (lane m+16q aggregates node n0+m, features q*8..+7)
// IS the MFMA B-fragment layout k_out used -> pack acc in-register, no LDS,
// no cross-lane traffic, no A2 round-trip through memory.
__global__ __launch_bounds__(256) void k_gather_out(
    const unsigned short* __restrict__ A1, const float* __restrict__ dinv,
    const int* __restrict__ start, const int* __restrict__ endp,
    const int2* __restrict__ srcw,
    const float* __restrict__ x, const float* __restrict__ Wup,
    const float* __restrict__ bup, float* __restrict__ out, int N)
{
    int gw   = (blockIdx.x * 256 + threadIdx.x) >> 6;  // wave id = 16-node tile
    int lane = threadIdx.x & 63;
    int m = lane & 15, q = lane >> 4, jq = q * 8;
    int tiles = (N + 15) >> 4;
    if (gw >= tiles) return;
    int n0 = gw << 4;
    int n = n0 + m;
    bool ok = n < N;
    int nc = ok ? n : N - 1;

    // ---- gather phase: acc[8] = aggregated h1 features for (node nc, jq) ----
    float di = dinv[nc];
    float w0 = di * di;
    float acc[8];
    ushort8 sv = *(const ushort8*)(A1 + (size_t)nc * BOT + jq);
    #pragma unroll
    for (int i = 0; i < 8; ++i) acc[i] = w0 * bu2f(sv[i]);
    int k = start[nc], en = endp[nc];
    while (k < en) {
        int2 p[4];
        #pragma unroll
        for (int u = 0; u < 4; ++u) {
            int kk = k + u;
            int safe = kk < en ? kk : en - 1;
            p[u] = srcw[safe];
            if (kk >= en) p[u].y = 0;
        }
        ushort8 f[4];
        #pragma unroll
        for (int u = 0; u < 4; ++u)
            f[u] = *(const ushort8*)(A1 + (size_t)p[u].x * BOT + jq);
        #pragma unroll
        for (int u = 0; u < 4; ++u) {
            float w = __int_as_float(p[u].y);
            #pragma unroll
            for (int i = 0; i < 8; ++i) acc[i] += w * bu2f(f[u][i]);
        }
        k += 4;
    }

    // ---- pack to the MFMA B-fragment (identical bits to the old A2 path) ----
    short8 af;
    #pragma unroll
    for (int i = 0; i < 8; ++i) af[i] = (short)f2bu(acc[i]);

    // ---- up-projection + bias + skip, NT store ----
    const float4* xrow = (const float4*)(x + (size_t)nc * HID);
    floatx4* orow = (floatx4*)(out + (size_t)nc * HID);
    #pragma unroll
    for (int ft = 0; ft < 16; ++ft) {
        const float4* wr = (const float4*)(Wup + (size_t)(ft * 16 + m) * BOT);
        short8 bfr = pack8(wr[q * 2], wr[q * 2 + 1]);
        floatx4 a = {0.f, 0.f, 0.f, 0.f};
        a = __builtin_amdgcn_mfma_f32_16x16x32_bf16(bfr, af, a, 0, 0, 0);
        // D: col=m -> node n0+m; row=q*4+r -> f = ft*16 + q*4 + r
        if (ok) {
            int c = ft * 4 + q;
            float4 xv = xrow[c];
            float4 bb = *(const float4*)(bup + ft * 16 + q * 4);
            floatx4 res;
            res[0] = a[0] + bb.x + xv.x;
            res[1] = a[1] + bb.y + xv.y;
            res[2] = a[2] + bb.z + xv.z;
            res[3] = a[3] + bb.w + xv.w;
            __builtin_nontemporal_store(res, &orow[c]);
        }
    }
}

extern "C" void kernel_launch(void* const* d_in, const int* in_sizes, int n_in,
                              void* d_out, int out_size, void* d_ws, size_t ws_size,
                              hipStream_t stream) {
    const float* x  = (const float*)d_in[0];
    const int*   ei = (const int*)d_in[1];
    const float* Wd = (const float*)d_in[2];
    const float* bd = (const float*)d_in[3];
    const float* Wu = (const float*)d_in[4];
    const float* bu = (const float*)d_in[5];
    float* out = (float*)d_out;

    int N = in_sizes[0] / HID;   // 100000
    int E = in_sizes[1] / 2;     // 800000

    char* ws = (char*)d_ws;
    int*   flags = (int*)ws;                                  // flags[1] = CSR cursor
    int*   deg   = (int*)(ws + 16);
    float* dinv  = (float*)(ws + 16 + (size_t)N * 4);
    int*   startp= (int*)(ws + 16 + (size_t)N * 8);
    int*   curp  = (int*)(ws + 16 + (size_t)N * 12);
    int2*  srcw  = (int2*)(ws + 16 + (size_t)N * 16);
    unsigned short* P  = (unsigned short*)(ws + 16 + (size_t)N * 16 + (size_t)E * 8);
    unsigned short* A1 = (unsigned short*)(ws + 16 + (size_t)N * 16 + (size_t)E * 8 + (size_t)N * 64);

    (void)hipMemsetAsync(ws, 0, 16 + (size_t)N * 4, stream);  // flags + cursor + deg

    int eblocks = (E + 255) / 256;              // 1 edge per thread (TLP!)
    k_deg<<<eblocks, 256, 0, stream>>>(ei, E, deg);

    // CSR region alloc + dinv
    k_alloc<<<(N + 255) / 256, 256, 0, stream>>>(deg, dinv, startp, curp, flags + 1, N);

    // Fused: down-GEMM (independent of CSR) + CSR fill, co-scheduled
    int tiles = (N + 15) / 16;                  // 6250
    int gemmBlocks = (tiles + 3) / 4;           // 1 tile per wave -> 1563
    k_fill_gemm<<<gemmBlocks + eblocks, 256, 0, stream>>>(
        ei, E, dinv, curp, srcw, x, Wd, P, N, gemmBlocks, gemmBlocks * 4);

    // Layer 1 aggregate: h1 = relu(gather(P) + bd)
    int gthreads = N * 4;                       // 4 threads per node
    k_gather<<<(gthreads + 255) / 256, 256, 0, stream>>>(P, dinv, startp, curp, srcw, bd, A1, N, 1);

    // Layer 2 aggregate + up-proj + bias + skip, fused (one wave per 16 nodes)
    int oblocks = (tiles + 3) / 4;              // 1563
    k_gather_out<<<oblocks, 256, 0, stream>>>(A1, dinv, startp, curp, srcw, x, Wu, bu, out, N);
}

// Round 8
// 349.163 us; speedup vs baseline: 1.1826x; 1.0124x over previous
//
#include <hip/hip_runtime.h>
#include <hip/hip_bf16.h>
#include <stdint.h>

#define HID 256
#define BOT 32

typedef short short8 __attribute__((ext_vector_type(8)));
typedef unsigned short ushort8 __attribute__((ext_vector_type(8)));
typedef float floatx4 __attribute__((ext_vector_type(4)));

// fp32 -> bf16 raw bits (truncate; ~2^-8 rel err, irrelevant at 1e-5 weight scale)
__device__ __forceinline__ unsigned short f2bu(float f) {
    return (unsigned short)(__float_as_uint(f) >> 16);
}
__device__ __forceinline__ float bu2f(unsigned short u) {
    return __uint_as_float((unsigned int)u << 16);
}
// pack 8 consecutive fp32 (two float4) into a bf16 short8 fragment
__device__ __forceinline__ short8 pack8(float4 a, float4 b) {
    short8 r;
    r[0] = (short)f2bu(a.x); r[1] = (short)f2bu(a.y);
    r[2] = (short)f2bu(a.z); r[3] = (short)f2bu(a.w);
    r[4] = (short)f2bu(b.x); r[5] = (short)f2bu(b.y);
    r[6] = (short)f2bu(b.z); r[7] = (short)f2bu(b.w);
    return r;
}

// Per-block int64-vs-int32 detection: int64 values < 2^31 have all-zero high
// words; check the first 512 odd int slots (L2-hot, one wave does it).
__device__ __forceinline__ int detect_mode(const int* __restrict__ ei, int* smode) {
    if (threadIdx.x < 64) {
        int found = 0;
        #pragma unroll
        for (int i = 0; i < 8; ++i) {
            int slot = 2 * (threadIdx.x * 8 + i) + 1;
            if (ei[slot] != 0) found = 1;
        }
        unsigned long long b = __ballot(found);
        if (threadIdx.x == 0) *smode = (b == 0ULL) ? 1 : 0;
    }
    __syncthreads();
    return *smode;
}

// ---------------------------------------------------------------------------
// ws layout (N=100000, E=800000 -> ~24 MB):
//   [0)              int    flags[4]  (flags[1]: CSR cursor for alloc)
//   [16)             int    deg[N]
//   [16+4N)          float  dinv[N]
//   [16+8N)          int    start[N]
//   [16+12N)         int    eslot[E]    (within-dst slot, from k_deg's atomic)
//   [16+12N+4E)      int2   srcw[E]     (src, norm-weight bits)
//   [16+12N+12E)     ushort P[N*32]     (bf16; layer-1 proj)
//   [16+12N+12E+64N) ushort A1[N*32]    (bf16; layer-1 aggregate -> h1)
// ---------------------------------------------------------------------------

// 1 edge/thread (max TLP for the random-atomic chain). Also records the
// within-dst slot so k_fill needs NO second atomic pass.
__global__ __launch_bounds__(256) void k_deg(const int* __restrict__ ei, int E,
                                             int* __restrict__ deg,
                                             int* __restrict__ eslot) {
    __shared__ int smode;
    int mode = detect_mode(ei, &smode);
    int e = blockIdx.x * 256 + threadIdx.x;
    if (e >= E) return;
    int d = mode ? ei[2 * (size_t)E + 2 * e] : ei[(size_t)E + e];
    eslot[e] = atomicAdd(deg + d, 1);
}

// Per-node CSR region allocation (block scan + one global atomic) + dinv fused.
__global__ __launch_bounds__(256) void k_alloc(const int* __restrict__ deg,
                                               float* __restrict__ dinv,
                                               int* __restrict__ start,
                                               int* __restrict__ cursor, int N) {
    __shared__ int sdata[256];
    __shared__ int sbase;
    int tid = threadIdx.x;
    int i = blockIdx.x * 256 + tid;
    int d = (i < N) ? deg[i] : 0;
    if (i < N) dinv[i] = rsqrtf((float)(d + 1));  // +1 self-loop
    sdata[tid] = d;
    __syncthreads();
    for (int off = 1; off < 256; off <<= 1) {
        int t = (tid >= off) ? sdata[tid - off] : 0;
        __syncthreads();
        sdata[tid] += t;
        __syncthreads();
    }
    if (tid == 0) sbase = atomicAdd(cursor, sdata[255]);
    __syncthreads();
    if (i < N) start[i] = sbase + sdata[tid] - d;
}

// Atomic-free CSR fill: slot = start[d] + eslot[e]. 1 edge/thread, low VGPR ->
// max occupancy for the latency-bound scatter (round-6 lesson: never share a
// register allocation between this and the GEMM).
__global__ __launch_bounds__(256) void k_fill(const int* __restrict__ ei, int E,
                                              const float* __restrict__ dinv,
                                              const int* __restrict__ start,
                                              const int* __restrict__ eslot,
                                              int2* __restrict__ srcw) {
    __shared__ int smode;
    int mode = detect_mode(ei, &smode);
    int e = blockIdx.x * 256 + threadIdx.x;
    if (e >= E) return;
    int s, d;
    if (mode) { s = ei[2 * (size_t)e]; d = ei[2 * (size_t)E + 2 * e]; }
    else      { s = ei[(size_t)e];     d = ei[(size_t)E + e]; }
    float w = dinv[s] * dinv[d];
    int slot = start[d] + eslot[e];
    srcw[slot] = make_int2(s, __float_as_int(w));
}

// P[n,j] = sum_k x[n,k]*Wd[j,k] via mfma 16x16x32 bf16, SWAPPED operands:
// D[j_local][n_local] -> lane holds 4 consecutive j for one node -> 8B stores.
// Cached x loads populate L3 so k_gather_out's re-read of x is L3-hot.
__global__ __launch_bounds__(256) void k_gemm_down(
    const float* __restrict__ x, const float* __restrict__ Wd,
    unsigned short* __restrict__ P, int N, int nwaves)
{
    int wid  = (blockIdx.x * 256 + threadIdx.x) >> 6;
    int lane = threadIdx.x & 63;
    int m = lane & 15, q = lane >> 4;

    short8 bfr[2][8];   // lane m holds Wd[jt*16+m][k=ks*32+q*8..+7]
    #pragma unroll
    for (int jt = 0; jt < 2; ++jt) {
        const float4* wr = (const float4*)(Wd + (size_t)(jt * 16 + m) * HID);
        #pragma unroll
        for (int ks = 0; ks < 8; ++ks) {
            int c = (ks * 32 + q * 8) >> 2;
            bfr[jt][ks] = pack8(wr[c], wr[c + 1]);
        }
    }

    int tiles = (N + 15) >> 4;
    for (int t = wid; t < tiles; t += nwaves) {
        int n0 = t << 4;
        int row = n0 + m; if (row >= N) row = N - 1;
        const float4* xr = (const float4*)(x + (size_t)row * HID);
        floatx4 acc0 = {0.f, 0.f, 0.f, 0.f};
        floatx4 acc1 = {0.f, 0.f, 0.f, 0.f};
        #pragma unroll
        for (int ks = 0; ks < 8; ++ks) {
            int c = (ks * 32 + q * 8) >> 2;
            short8 af = pack8(xr[c], xr[c + 1]);   // B[k][n=m] = x[n0+m][k]
            acc0 = __builtin_amdgcn_mfma_f32_16x16x32_bf16(bfr[0][ks], af, acc0, 0, 0, 0);
            acc1 = __builtin_amdgcn_mfma_f32_16x16x32_bf16(bfr[1][ks], af, acc1, 0, 0, 0);
        }
        if (n0 + m < N) {
            unsigned int* pr = (unsigned int*)(P + (size_t)(n0 + m) * BOT);
            uint2 v0, v1;
            v0.x = (unsigned int)f2bu(acc0[0]) | ((unsigned int)f2bu(acc0[1]) << 16);
            v0.y = (unsigned int)f2bu(acc0[2]) | ((unsigned int)f2bu(acc0[3]) << 16);
            v1.x = (unsigned int)f2bu(acc1[0]) | ((unsigned int)f2bu(acc1[1]) << 16);
            v1.y = (unsigned int)f2bu(acc1[2]) | ((unsigned int)f2bu(acc1[3]) << 16);
            *(uint2*)(pr + q * 2)     = v0;   // j = q*4..q*4+3
            *(uint2*)(pr + 8 + q * 2) = v1;   // j = 16+q*4..16+q*4+3
        }
    }
}

// Gather-aggregate over CSR: 4 threads per node, each owns 8 of 32 features.
// Masked unroll-4: 4 independent srcw loads + 4 independent 16B gathers/iter.
__global__ __launch_bounds__(256) void k_gather(
    const unsigned short* __restrict__ feat, const float* __restrict__ dinv,
    const int* __restrict__ start, const int* __restrict__ cnt,
    const int2* __restrict__ srcw, const float* __restrict__ bias,
    unsigned short* __restrict__ dst, int N, int relu_bias)
{
    int t = blockIdx.x * 256 + threadIdx.x;
    int n = t >> 2, jq = (t & 3) * 8;
    if (n >= N) return;
    float di = dinv[n];
    float w0 = di * di;
    float acc[8];
    ushort8 sv = *(const ushort8*)(feat + (size_t)n * BOT + jq);
    #pragma unroll
    for (int i = 0; i < 8; ++i) acc[i] = w0 * bu2f(sv[i]);
    int k = start[n], en = k + cnt[n];
    while (k < en) {
        int2 p[4];
        #pragma unroll
        for (int u = 0; u < 4; ++u) {
            int kk = k + u;
            int safe = kk < en ? kk : en - 1;   // en-1 valid: loop entered => deg>0
            p[u] = srcw[safe];
            if (kk >= en) p[u].y = 0;          // weight 0 for masked lanes
        }
        ushort8 f[4];
        #pragma unroll
        for (int u = 0; u < 4; ++u)
            f[u] = *(const ushort8*)(feat + (size_t)p[u].x * BOT + jq);
        #pragma unroll
        for (int u = 0; u < 4; ++u) {
            float w = __int_as_float(p[u].y);
            #pragma unroll
            for (int i = 0; i < 8; ++i) acc[i] += w * bu2f(f[u][i]);
        }
        k += 4;
    }
    if (relu_bias) {
        #pragma unroll
        for (int i = 0; i < 8; ++i) {
            float a = acc[i] + bias[jq + i];
            acc[i] = a > 0.f ? a : 0.f;
        }
    }
    ushort8 o;
    #pragma unroll
    for (int i = 0; i < 8; ++i) o[i] = f2bu(acc[i]);
    *(ushort8*)(dst + (size_t)n * BOT + jq) = o;
}

// FUSED gather-2 + up-projection + skip: out[n,:] depends only on A2[n,:], and
// the gather lane layout (lane m+16q aggregates node n0+m, features q*8..+7)
// IS the MFMA B-fragment layout -> pack acc in-register, no LDS, no A2
// round-trip through memory.
__global__ __launch_bounds__(256) void k_gather_out(
    const unsigned short* __restrict__ A1, const float* __restrict__ dinv,
    const int* __restrict__ start, const int* __restrict__ cnt,
    const int2* __restrict__ srcw,
    const float* __restrict__ x, const float* __restrict__ Wup,
    const float* __restrict__ bup, float* __restrict__ out, int N)
{
    int gw   = (blockIdx.x * 256 + threadIdx.x) >> 6;  // wave id = 16-node tile
    int lane = threadIdx.x & 63;
    int m = lane & 15, q = lane >> 4, jq = q * 8;
    int tiles = (N + 15) >> 4;
    if (gw >= tiles) return;
    int n0 = gw << 4;
    int n = n0 + m;
    bool ok = n < N;
    int nc = ok ? n : N - 1;

    // ---- gather phase: acc[8] = aggregated h1 features for (node nc, jq) ----
    float di = dinv[nc];
    float w0 = di * di;
    float acc[8];
    ushort8 sv = *(const ushort8*)(A1 + (size_t)nc * BOT + jq);
    #pragma unroll
    for (int i = 0; i < 8; ++i) acc[i] = w0 * bu2f(sv[i]);
    int k = start[nc], en = k + cnt[nc];
    while (k < en) {
        int2 p[4];
        #pragma unroll
        for (int u = 0; u < 4; ++u) {
            int kk = k + u;
            int safe = kk < en ? kk : en - 1;
            p[u] = srcw[safe];
            if (kk >= en) p[u].y = 0;
        }
        ushort8 f[4];
        #pragma unroll
        for (int u = 0; u < 4; ++u)
            f[u] = *(const ushort8*)(A1 + (size_t)p[u].x * BOT + jq);
        #pragma unroll
        for (int u = 0; u < 4; ++u) {
            float w = __int_as_float(p[u].y);
            #pragma unroll
            for (int i = 0; i < 8; ++i) acc[i] += w * bu2f(f[u][i]);
        }
        k += 4;
    }

    // ---- pack to the MFMA B-fragment (identical bits to a memory A2 path) ----
    short8 af;
    #pragma unroll
    for (int i = 0; i < 8; ++i) af[i] = (short)f2bu(acc[i]);

    // ---- up-projection + bias + skip, NT store ----
    const float4* xrow = (const float4*)(x + (size_t)nc * HID);
    floatx4* orow = (floatx4*)(out + (size_t)nc * HID);
    #pragma unroll
    for (int ft = 0; ft < 16; ++ft) {
        const float4* wr = (const float4*)(Wup + (size_t)(ft * 16 + m) * BOT);
        short8 bfr = pack8(wr[q * 2], wr[q * 2 + 1]);
        floatx4 a = {0.f, 0.f, 0.f, 0.f};
        a = __builtin_amdgcn_mfma_f32_16x16x32_bf16(bfr, af, a, 0, 0, 0);
        // D: col=m -> node n0+m; row=q*4+r -> f = ft*16 + q*4 + r
        if (ok) {
            int c = ft * 4 + q;
            float4 xv = xrow[c];
            float4 bb = *(const float4*)(bup + ft * 16 + q * 4);
            floatx4 res;
            res[0] = a[0] + bb.x + xv.x;
            res[1] = a[1] + bb.y + xv.y;
            res[2] = a[2] + bb.z + xv.z;
            res[3] = a[3] + bb.w + xv.w;
            __builtin_nontemporal_store(res, &orow[c]);
        }
    }
}

extern "C" void kernel_launch(void* const* d_in, const int* in_sizes, int n_in,
                              void* d_out, int out_size, void* d_ws, size_t ws_size,
                              hipStream_t stream) {
    const float* x  = (const float*)d_in[0];
    const int*   ei = (const int*)d_in[1];
    const float* Wd = (const float*)d_in[2];
    const float* bd = (const float*)d_in[3];
    const float* Wu = (const float*)d_in[4];
    const float* bu = (const float*)d_in[5];
    float* out = (float*)d_out;

    int N = in_sizes[0] / HID;   // 100000
    int E = in_sizes[1] / 2;     // 800000

    char* ws = (char*)d_ws;
    int*   flags = (int*)ws;                                  // flags[1] = alloc cursor
    int*   deg   = (int*)(ws + 16);
    float* dinv  = (float*)(ws + 16 + (size_t)N * 4);
    int*   startp= (int*)(ws + 16 + (size_t)N * 8);
    int*   eslot = (int*)(ws + 16 + (size_t)N * 12);
    int2*  srcw  = (int2*)(ws + 16 + (size_t)N * 12 + (size_t)E * 4);
    unsigned short* P  = (unsigned short*)(ws + 16 + (size_t)N * 12 + (size_t)E * 12);
    unsigned short* A1 = (unsigned short*)(ws + 16 + (size_t)N * 12 + (size_t)E * 12 + (size_t)N * 64);

    (void)hipMemsetAsync(ws, 0, 16 + (size_t)N * 4, stream);  // flags + deg

    int eblocks = (E + 255) / 256;              // 1 edge per thread (TLP!)
    k_deg<<<eblocks, 256, 0, stream>>>(ei, E, deg, eslot);

    // CSR region alloc + dinv
    k_alloc<<<(N + 255) / 256, 256, 0, stream>>>(deg, dinv, startp, flags + 1, N);

    // CSR fill: atomic-free, low-VGPR, standalone (occupancy!)
    k_fill<<<eblocks, 256, 0, stream>>>(ei, E, dinv, startp, eslot, srcw);

    // Down-GEMM: P = x @ Wd^T (2 tiles/wave, weight frags amortized)
    int tiles = (N + 15) / 16;                  // 6250
    int gblocks = 782;                          // 3128 waves ~ 2 tiles/wave
    k_gemm_down<<<gblocks, 256, 0, stream>>>(x, Wd, P, N, gblocks * 4);

    // Layer 1 aggregate: h1 = relu(gather(P) + bd)
    int gthreads = N * 4;                       // 4 threads per node
    k_gather<<<(gthreads + 255) / 256, 256, 0, stream>>>(P, dinv, startp, deg, srcw, bd, A1, N, 1);

    // Layer 2 aggregate + up-proj + bias + skip, fused (one wave per 16 nodes)
    int oblocks = (tiles + 3) / 4;              // 1563
    k_gather_out<<<oblocks, 256, 0, stream>>>(A1, dinv, startp, deg, srcw, x, Wu, bu, out, N);
}